// Round 10
// baseline (341.035 us; speedup 1.0000x reference)
//
#include <hip/hip_runtime.h>
#include <math.h>

#define BB 32
#define CC 3
#define HH 512
#define WW 512

// 8-byte load at 4-byte alignment (clang emits global_load_dwordx2, align 4).
struct f2 { float a, b; };
__device__ __forceinline__ f2 load_f2(const float* __restrict__ p) {
    f2 r;
    __builtin_memcpy(&r, p, sizeof(f2));
    return r;
}

// ---------------------------------------------------------------------------
// Kernel 1: 3x3 matrix exponential, one matrix per thread, double precision
// scaling-and-squaring + fully-unrolled 14-term Taylor.
// ---------------------------------------------------------------------------
__global__ void expm_kernel(const float* __restrict__ theta, float* __restrict__ E) {
    int b = threadIdx.x;
    if (b >= BB) return;

    double A[3][3];
#pragma unroll
    for (int j = 0; j < 2; ++j)
#pragma unroll
        for (int k = 0; k < 3; ++k)
            A[j][k] = (double)theta[b * 6 + j * 3 + k];
    A[2][0] = A[2][1] = A[2][2] = 0.0;

    double nrm = 0.0;
#pragma unroll
    for (int i = 0; i < 3; ++i) {
        double r = fabs(A[i][0]) + fabs(A[i][1]) + fabs(A[i][2]);
        nrm = fmax(nrm, r);
    }
    int s = 0;
    while (nrm > 0.5) { nrm *= 0.5; ++s; }
    double sc = ldexp(1.0, -s);
#pragma unroll
    for (int i = 0; i < 3; ++i)
#pragma unroll
        for (int k = 0; k < 3; ++k) A[i][k] *= sc;

    double R[3][3] = {{1, 0, 0}, {0, 1, 0}, {0, 0, 1}};
    double T[3][3] = {{1, 0, 0}, {0, 1, 0}, {0, 0, 1}};
#pragma unroll
    for (int k = 1; k <= 14; ++k) {
        double N[3][3];
        const double inv = 1.0 / (double)k;  // compile-time (unrolled)
#pragma unroll
        for (int i = 0; i < 3; ++i)
#pragma unroll
            for (int j = 0; j < 3; ++j)
                N[i][j] = (T[i][0] * A[0][j] + T[i][1] * A[1][j] + T[i][2] * A[2][j]) * inv;
#pragma unroll
        for (int i = 0; i < 3; ++i)
#pragma unroll
            for (int j = 0; j < 3; ++j) {
                T[i][j] = N[i][j];
                R[i][j] += N[i][j];
            }
    }
    for (int q = 0; q < s; ++q) {
        double N[3][3];
#pragma unroll
        for (int i = 0; i < 3; ++i)
#pragma unroll
            for (int j = 0; j < 3; ++j)
                N[i][j] = R[i][0] * R[0][j] + R[i][1] * R[1][j] + R[i][2] * R[2][j];
#pragma unroll
        for (int i = 0; i < 3; ++i)
#pragma unroll
            for (int j = 0; j < 3; ++j) R[i][j] = N[i][j];
    }

#pragma unroll
    for (int j = 0; j < 2; ++j)
#pragma unroll
        for (int k = 0; k < 3; ++k)
            E[b * 6 + j * 3 + k] = (float)R[j][k];
}

// ---------------------------------------------------------------------------
// Kernel 2: affine grid + bilinear sample. Per 16x16 output tile, compute the
// source-footprint bbox from the 4 tile corners (affine -> extrema at
// corners). If bbox fits 64x64 (block-uniform test), cooperatively load it
// into LDS with coalesced row loads (TA-cheap), then bilinear-gather from LDS
// (LDS pipe, not TA). Fallback: direct divergent global gather (round-9
// path). Empty-footprint tiles store zeros with no loads.
// Wave = 8x8 px quad, block = 16x16 tile, grid = 32 batches x 1024 tiles.
// ---------------------------------------------------------------------------
__global__ __launch_bounds__(256) void st_sample_kernel(const float* __restrict__ x,
                                                        const float* __restrict__ E,
                                                        float* __restrict__ out) {
    __shared__ float lds[CC * 64 * 64];  // 48 KB

    const int bid = blockIdx.x;
    const int b = bid >> 10;            // wave-uniform
    const int t = bid & 1023;
    const int tileY = t >> 5, tileX = t & 31;
    const int tx0 = tileX << 4, ty0 = tileY << 4;

    const int tid = threadIdx.x;
    const int wv = tid >> 6, lane = tid & 63;
    const int px = tx0 + ((wv & 1) << 3) + (lane & 7);
    const int py = ty0 + ((wv >> 1) << 3) + (lane >> 3);

    const float t00 = E[b * 6 + 0], t01 = E[b * 6 + 1], t02 = E[b * 6 + 2];
    const float t10 = E[b * 6 + 3], t11 = E[b * 6 + 4], t12 = E[b * 6 + 5];

    const float* __restrict__ xb = x + (size_t)b * CC * HH * WW;

    // ---- block-uniform bbox of the tile's source footprint ----
    const float cgx0 = (2.0f * (float)tx0 + 1.0f) * (1.0f / (float)WW) - 1.0f;
    const float cgx1 = (2.0f * (float)(tx0 + 15) + 1.0f) * (1.0f / (float)WW) - 1.0f;
    const float cgy0 = (2.0f * (float)ty0 + 1.0f) * (1.0f / (float)HH) - 1.0f;
    const float cgy1 = (2.0f * (float)(ty0 + 15) + 1.0f) * (1.0f / (float)HH) - 1.0f;
    #define CIX(gx, gy) (((t00 * (gx) + t01 * (gy) + t02) + 1.0f) * ((float)WW * 0.5f) - 0.5f)
    #define CIY(gx, gy) (((t10 * (gx) + t11 * (gy) + t12) + 1.0f) * ((float)HH * 0.5f) - 0.5f)
    const float ix00 = CIX(cgx0, cgy0), ix10 = CIX(cgx1, cgy0), ix01 = CIX(cgx0, cgy1), ix11 = CIX(cgx1, cgy1);
    const float iy00 = CIY(cgx0, cgy0), iy10 = CIY(cgx1, cgy0), iy01 = CIY(cgx0, cgy1), iy11 = CIY(cgx1, cgy1);
    const float min_ix = fminf(fminf(ix00, ix10), fminf(ix01, ix11));
    const float max_ix = fmaxf(fmaxf(ix00, ix10), fmaxf(ix01, ix11));
    const float min_iy = fminf(fminf(iy00, iy10), fminf(iy01, iy11));
    const float max_iy = fmaxf(fmaxf(iy00, iy10), fmaxf(iy01, iy11));
    const int fb_x0 = (int)floorf(min_ix), fb_x1 = (int)floorf(max_ix) + 1;
    const int fb_y0 = (int)floorf(min_iy), fb_y1 = (int)floorf(max_iy) + 1;
    const bool empty = (fb_x1 < 0) | (fb_x0 > WW - 1) | (fb_y1 < 0) | (fb_y0 > HH - 1);
    const int bb_x0 = max(fb_x0, 0), bb_x1 = min(fb_x1, WW - 1);
    const int bb_y0 = max(fb_y0, 0), bb_y1 = min(fb_y1, HH - 1);
    const int bw = bb_x1 - bb_x0 + 1, bh = bb_y1 - bb_y0 + 1;
    const bool use_lds = (!empty) & (bw <= 64) & (bh <= 64);

    if (use_lds) {
        // cooperative coalesced load: lane = column, wave = row group
#pragma unroll
        for (int c = 0; c < CC; ++c) {
            const float* __restrict__ xc = xb + c * (HH * WW) + (size_t)bb_y0 * WW + bb_x0;
            float* __restrict__ lc = lds + c * 4096;
            for (int r = wv; r < bh; r += 4) {
                if (lane < bw) lc[(r << 6) + lane] = xc[r * WW + lane];
            }
        }
        __syncthreads();
    }

    // ---- per-pixel sample ----
    const float gx = (2.0f * (float)px + 1.0f) * (1.0f / (float)WW) - 1.0f;
    const float gy = (2.0f * (float)py + 1.0f) * (1.0f / (float)HH) - 1.0f;
    const float ix = CIX(gx, gy);
    const float iy = CIY(gx, gy);

    float acc[CC] = {0.0f, 0.0f, 0.0f};

    const bool any = (ix > -1.0f) & (ix < (float)WW) & (iy > -1.0f) & (iy < (float)HH);
    if (any) {
        float x0f = floorf(ix), y0f = floorf(iy);
        float x1f = x0f + 1.0f, y1f = y0f + 1.0f;
        float wa = (x1f - ix) * (y1f - iy);
        float wb = (x1f - ix) * (iy - y0f);
        float wc = (ix - x0f) * (y1f - iy);
        float wd = (ix - x0f) * (iy - y0f);

        float mx0 = (x0f >= 0.0f) ? 1.0f : 0.0f;
        float mx1 = (x1f <= (float)(WW - 1)) ? 1.0f : 0.0f;
        float my0 = (y0f >= 0.0f) ? 1.0f : 0.0f;
        float my1 = (y1f <= (float)(HH - 1)) ? 1.0f : 0.0f;

        int xi0 = (int)fminf(fmaxf(x0f, 0.0f), (float)(WW - 1));
        int xi1 = (int)fminf(fmaxf(x1f, 0.0f), (float)(WW - 1));
        int yi0 = (int)fminf(fmaxf(y0f, 0.0f), (float)(HH - 1));
        int yi1 = (int)fminf(fmaxf(y1f, 0.0f), (float)(HH - 1));

        float wA = wa * mx0 * my0;
        float wB = wb * mx0 * my1;
        float wC = wc * mx1 * my0;
        float wD = wd * mx1 * my1;

        if (use_lds) {
            const int lx0 = xi0 - bb_x0, lx1 = xi1 - bb_x0;
            const int r0 = (yi0 - bb_y0) << 6, r1 = (yi1 - bb_y0) << 6;
#pragma unroll
            for (int c = 0; c < CC; ++c) {
                const float* __restrict__ lc = lds + c * 4096;
                float v00 = lc[r0 + lx0];
                float v10 = lc[r0 + lx1];
                float v01 = lc[r1 + lx0];
                float v11 = lc[r1 + lx1];
                acc[c] = wA * v00 + wB * v01 + wC * v10 + wD * v11;
            }
        } else {
            int bx = min(xi0, WW - 2);
            int d0 = xi0 - bx, d1 = xi1 - bx;
            int ib0 = yi0 * WW + bx, ib1 = yi1 * WW + bx;
            f2 r0[CC], r1[CC];
#pragma unroll
            for (int c = 0; c < CC; ++c) {
                const float* __restrict__ xc = xb + c * (HH * WW);
                r0[c] = load_f2(xc + ib0);
                r1[c] = load_f2(xc + ib1);
            }
#pragma unroll
            for (int c = 0; c < CC; ++c) {
                float v00 = d0 ? r0[c].b : r0[c].a;
                float v10 = d1 ? r0[c].b : r0[c].a;
                float v01 = d0 ? r1[c].b : r1[c].a;
                float v11 = d1 ? r1[c].b : r1[c].a;
                acc[c] = wA * v00 + wB * v01 + wC * v10 + wD * v11;
            }
        }
    }

    const size_t obase = ((size_t)b * CC) * (HH * WW) + (size_t)py * WW + px;
#pragma unroll
    for (int c = 0; c < CC; ++c)
        out[obase + (size_t)c * (HH * WW)] = acc[c];
}

extern "C" void kernel_launch(void* const* d_in, const int* in_sizes, int n_in,
                              void* d_out, int out_size, void* d_ws, size_t ws_size,
                              hipStream_t stream) {
    const float* x = (const float*)d_in[0];
    const float* theta = (const float*)d_in[1];
    float* out = (float*)d_out;
    float* E = (float*)d_ws;  // 32*6 floats

    expm_kernel<<<1, 64, 0, stream>>>(theta, E);

    const int nblocks = BB * 32 * 32;   // 32768 blocks of 256 threads
    st_sample_kernel<<<nblocks, 256, 0, stream>>>(x, E, out);
}

// Round 11
// 228.866 us; speedup vs baseline: 1.4901x; 1.4901x over previous
//
#include <hip/hip_runtime.h>
#include <math.h>

#define BB 32
#define CC 3
#define HH 512
#define WW 512

// 8-byte load at 4-byte alignment (clang emits global_load_dwordx2, align 4).
struct f2 { float a, b; };
__device__ __forceinline__ f2 load_f2(const float* __restrict__ p) {
    f2 r;
    __builtin_memcpy(&r, p, sizeof(f2));
    return r;
}

// ---------------------------------------------------------------------------
// Kernel 1: 3x3 matrix exponential, one matrix per thread, double precision
// scaling-and-squaring + fully-unrolled 14-term Taylor.
// ---------------------------------------------------------------------------
__global__ void expm_kernel(const float* __restrict__ theta, float* __restrict__ E) {
    int b = threadIdx.x;
    if (b >= BB) return;

    double A[3][3];
#pragma unroll
    for (int j = 0; j < 2; ++j)
#pragma unroll
        for (int k = 0; k < 3; ++k)
            A[j][k] = (double)theta[b * 6 + j * 3 + k];
    A[2][0] = A[2][1] = A[2][2] = 0.0;

    double nrm = 0.0;
#pragma unroll
    for (int i = 0; i < 3; ++i) {
        double r = fabs(A[i][0]) + fabs(A[i][1]) + fabs(A[i][2]);
        nrm = fmax(nrm, r);
    }
    int s = 0;
    while (nrm > 0.5) { nrm *= 0.5; ++s; }
    double sc = ldexp(1.0, -s);
#pragma unroll
    for (int i = 0; i < 3; ++i)
#pragma unroll
        for (int k = 0; k < 3; ++k) A[i][k] *= sc;

    double R[3][3] = {{1, 0, 0}, {0, 1, 0}, {0, 0, 1}};
    double T[3][3] = {{1, 0, 0}, {0, 1, 0}, {0, 0, 1}};
#pragma unroll
    for (int k = 1; k <= 14; ++k) {
        double N[3][3];
        const double inv = 1.0 / (double)k;  // compile-time (unrolled)
#pragma unroll
        for (int i = 0; i < 3; ++i)
#pragma unroll
            for (int j = 0; j < 3; ++j)
                N[i][j] = (T[i][0] * A[0][j] + T[i][1] * A[1][j] + T[i][2] * A[2][j]) * inv;
#pragma unroll
        for (int i = 0; i < 3; ++i)
#pragma unroll
            for (int j = 0; j < 3; ++j) {
                T[i][j] = N[i][j];
                R[i][j] += N[i][j];
            }
    }
    for (int q = 0; q < s; ++q) {
        double N[3][3];
#pragma unroll
        for (int i = 0; i < 3; ++i)
#pragma unroll
            for (int j = 0; j < 3; ++j)
                N[i][j] = R[i][0] * R[0][j] + R[i][1] * R[1][j] + R[i][2] * R[2][j];
#pragma unroll
        for (int i = 0; i < 3; ++i)
#pragma unroll
            for (int j = 0; j < 3; ++j) R[i][j] = N[i][j];
    }

#pragma unroll
    for (int j = 0; j < 2; ++j)
#pragma unroll
        for (int k = 0; k < 3; ++k)
            E[b * 6 + j * 3 + k] = (float)R[j][k];
}

// ---------------------------------------------------------------------------
// Kernel 2: affine grid + bilinear grid_sample (round-9 structure: 2D-tiled
// divergent gather, NO LDS) + persistent blocks. 2048 resident blocks
// grid-stride over 32768 16x16 tiles -> 32 waves/CU resident (vs ~18 with
// one-shot blocks) to hide gather latency; concurrently-active input working
// set ~2 batches (6 MB) -> better L2 locality.
// Wave = 8x8 px quad, block = 16x16 tile. 1 thread = 1 px x 3 channels.
// ---------------------------------------------------------------------------
#define NTILES (BB * 1024)
#define NBLOCKS 2048

__global__ __launch_bounds__(256) void st_sample_kernel(const float* __restrict__ x,
                                                        const float* __restrict__ E,
                                                        float* __restrict__ out) {
    const int tid = threadIdx.x;
    const int wv = tid >> 6, lane = tid & 63;
    const int lx = ((wv & 1) << 3) + (lane & 7);
    const int ly = ((wv >> 1) << 3) + (lane >> 3);

    for (int t5 = blockIdx.x; t5 < NTILES; t5 += NBLOCKS) {
        const int b = t5 >> 10;                 // block-uniform -> scalar path
        const int t = t5 & 1023;
        const int px = ((t & 31) << 4) + lx;
        const int py = ((t >> 5) << 4) + ly;

        const float t00 = E[b * 6 + 0], t01 = E[b * 6 + 1], t02 = E[b * 6 + 2];
        const float t10 = E[b * 6 + 3], t11 = E[b * 6 + 4], t12 = E[b * 6 + 5];

        const float* __restrict__ xb = x + (size_t)b * CC * HH * WW;

        const float gx = (2.0f * (float)px + 1.0f) * (1.0f / (float)WW) - 1.0f;
        const float gy = (2.0f * (float)py + 1.0f) * (1.0f / (float)HH) - 1.0f;
        const float grid_x = t00 * gx + t01 * gy + t02;
        const float grid_y = t10 * gx + t11 * gy + t12;
        const float ix = (grid_x + 1.0f) * ((float)WW * 0.5f) - 0.5f;
        const float iy = (grid_y + 1.0f) * ((float)HH * 0.5f) - 0.5f;

        float acc[CC] = {0.0f, 0.0f, 0.0f};

        const bool any = (ix > -1.0f) & (ix < (float)WW) & (iy > -1.0f) & (iy < (float)HH);
        if (any) {
            float x0f = floorf(ix), y0f = floorf(iy);
            float x1f = x0f + 1.0f, y1f = y0f + 1.0f;
            float wa = (x1f - ix) * (y1f - iy);
            float wb = (x1f - ix) * (iy - y0f);
            float wc = (ix - x0f) * (y1f - iy);
            float wd = (ix - x0f) * (iy - y0f);

            float mx0 = (x0f >= 0.0f) ? 1.0f : 0.0f;
            float mx1 = (x1f <= (float)(WW - 1)) ? 1.0f : 0.0f;
            float my0 = (y0f >= 0.0f) ? 1.0f : 0.0f;
            float my1 = (y1f <= (float)(HH - 1)) ? 1.0f : 0.0f;

            int xi0 = (int)fminf(fmaxf(x0f, 0.0f), (float)(WW - 1));
            int xi1 = (int)fminf(fmaxf(x1f, 0.0f), (float)(WW - 1));
            int yi0 = (int)fminf(fmaxf(y0f, 0.0f), (float)(HH - 1));
            int yi1 = (int)fminf(fmaxf(y1f, 0.0f), (float)(HH - 1));

            int bx = min(xi0, WW - 2);      // dwordx2 window [bx, bx+1], in-row
            int d0 = xi0 - bx;              // 0 or 1
            int d1 = xi1 - bx;              // 0 or 1
            int ib0 = yi0 * WW + bx;
            int ib1 = yi1 * WW + bx;

            float wA = wa * mx0 * my0;
            float wB = wb * mx0 * my1;
            float wC = wc * mx1 * my0;
            float wD = wd * mx1 * my1;

            // Issue all 6 loads back-to-back for MLP, then compute.
            f2 r0[CC], r1[CC];
#pragma unroll
            for (int c = 0; c < CC; ++c) {
                const float* __restrict__ xc = xb + c * (HH * WW);
                r0[c] = load_f2(xc + ib0);
                r1[c] = load_f2(xc + ib1);
            }
#pragma unroll
            for (int c = 0; c < CC; ++c) {
                float v00 = d0 ? r0[c].b : r0[c].a;
                float v10 = d1 ? r0[c].b : r0[c].a;
                float v01 = d0 ? r1[c].b : r1[c].a;
                float v11 = d1 ? r1[c].b : r1[c].a;
                acc[c] = wA * v00 + wB * v01 + wC * v10 + wD * v11;
            }
        }

        const size_t obase = ((size_t)b * CC) * (HH * WW) + (size_t)py * WW + px;
#pragma unroll
        for (int c = 0; c < CC; ++c)
            out[obase + (size_t)c * (HH * WW)] = acc[c];
    }
}

extern "C" void kernel_launch(void* const* d_in, const int* in_sizes, int n_in,
                              void* d_out, int out_size, void* d_ws, size_t ws_size,
                              hipStream_t stream) {
    const float* x = (const float*)d_in[0];
    const float* theta = (const float*)d_in[1];
    float* out = (float*)d_out;
    float* E = (float*)d_ws;  // 32*6 floats

    expm_kernel<<<1, 64, 0, stream>>>(theta, E);

    st_sample_kernel<<<NBLOCKS, 256, 0, stream>>>(x, E, out);
}